// Round 1
// 679.895 us; speedup vs baseline: 1.0003x; 1.0003x over previous
//
#include <hip/hip_runtime.h>

// Problem constants (fixed by reference): B=64, T=4096, D=512, fp32.
constexpr int B = 64;
constexpr int T = 4096;
constexpr int D = 512;
constexpr int CHUNKS = 16;                    // blocks per batch row
constexpr int ROWS_PER_CHUNK = T / CHUNKS;    // 256 t-rows per block
constexpr int PART_STRIDE = D + 2;            // [m, l, o[512]] per partial

__device__ __forceinline__ float dot8(const float4& a0, const float4& v0,
                                      const float4& a1, const float4& v1) {
    return a0.x * v0.x + a0.y * v0.y + a0.z * v0.z + a0.w * v0.w
         + a1.x * v1.x + a1.y * v1.y + a1.z * v1.z + a1.w * v1.w;
}

// ---------------------------------------------------------------------------
// Pass 1: fused GEMV-scores + online-softmax accumulation.
// Grid: B*CHUNKS = 1024 blocks of 256 threads (exactly 4 blocks/CU, all
// resident). Per iteration each wave processes 4 consecutive rows.
// Changes vs previous version (which ran ~4x off HBM roofline):
//   1. Manual double-buffered register prefetch (A/B buffers, statically
//      named): next iteration's 8 loads issue BEFORE the current
//      reduce/softmax chain, guaranteeing memory/compute overlap.
//   2. Defer-max (THR=10): no per-iteration corr rescale of l/o in the
//      common path; rescale only when running max grows >10 (wave-uniform
//      branch, since post-butterfly e[] is identical across lanes).
//   3. Wave-uniform skip of exp + o-FMAs when all 4 rows are < m-25
//      (contribution < 1.4e-11 relative -- invisible at fp32).
//   4. __launch_bounds__(256,4) pins <=128 VGPRs -> 4 waves/SIMD kept.
// ---------------------------------------------------------------------------
__global__ __launch_bounds__(256, 4) void attn_pass1(
    const float* __restrict__ enc,        // [B, T, D]
    const float* __restrict__ v,          // [D]
    float* __restrict__ energies,         // [B, T]  (d_out weights region)
    float* __restrict__ partials)         // [B*CHUNKS, PART_STRIDE]
{
    const int blk   = blockIdx.x;
    const int b     = blk / CHUNKS;
    const int chunk = blk % CHUNKS;
    const int tid   = threadIdx.x;
    const int wave  = tid >> 6;
    const int lane  = tid & 63;

    const float4 v0 = *(const float4*)(v + lane * 4);
    const float4 v1 = *(const float4*)(v + 256 + lane * 4);

    float  m = -3.0e38f;
    float  l = 0.0f;
    float4 o0 = make_float4(0.f, 0.f, 0.f, 0.f);
    float4 o1 = make_float4(0.f, 0.f, 0.f, 0.f);

    const int t0 = chunk * ROWS_PER_CHUNK;
    const float* encb = enc + (size_t)b * T * D;

    // Double-buffered row registers (statically named -- never runtime-indexed).
    float4 A0[4], A1[4], B0[4], B1[4];

#define LOADROWS(buf0, buf1, kk) do {                                          \
    const float* _row = encb + (size_t)(t0 + (kk) * 16 + wave * 4) * D         \
                        + lane * 4;                                            \
    _Pragma("unroll")                                                          \
    for (int _r = 0; _r < 4; ++_r) {                                           \
        buf0[_r] = *(const float4*)(_row + _r * D);                            \
        buf1[_r] = *(const float4*)(_row + _r * D + 256);                      \
    }                                                                          \
} while (0)

#define PROCESS(buf0, buf1, kk) do {                                           \
    float e[4];                                                                \
    _Pragma("unroll")                                                          \
    for (int _r = 0; _r < 4; ++_r)                                             \
        e[_r] = dot8(buf0[_r], v0, buf1[_r], v1);                              \
    /* 4 independent 64-lane butterfly reductions (ILP) */                     \
    _Pragma("unroll")                                                          \
    for (int _off = 32; _off > 0; _off >>= 1) {                                \
        _Pragma("unroll")                                                      \
        for (int _r = 0; _r < 4; ++_r)                                         \
            e[_r] += __shfl_xor(e[_r], _off, 64);                              \
    }                                                                          \
    if (lane == 0)                                                             \
        *(float4*)(energies + (size_t)b * T + (t0 + (kk) * 16 + wave * 4)) =   \
            make_float4(e[0], e[1], e[2], e[3]);                               \
    const float emax = fmaxf(fmaxf(e[0], e[1]), fmaxf(e[2], e[3]));            \
    /* rare, wave-uniform rescale (also handles first-iteration init:          \
       exp(-3e38 - emax) == 0 zeroes l/o exactly like before) */               \
    if (emax > m + 10.0f) {                                                    \
        const float _corr = __expf(m - emax);                                  \
        l *= _corr;                                                            \
        o0.x *= _corr; o0.y *= _corr; o0.z *= _corr; o0.w *= _corr;            \
        o1.x *= _corr; o1.y *= _corr; o1.z *= _corr; o1.w *= _corr;            \
        m = emax;                                                              \
    }                                                                          \
    /* wave-uniform skip: all 4 rows negligible vs running max */              \
    if (emax >= m - 25.0f) {                                                   \
        float p[4];                                                            \
        _Pragma("unroll")                                                      \
        for (int _r = 0; _r < 4; ++_r) p[_r] = __expf(e[_r] - m);              \
        l += p[0] + p[1] + p[2] + p[3];                                        \
        o0.x += p[0]*buf0[0].x + p[1]*buf0[1].x + p[2]*buf0[2].x + p[3]*buf0[3].x; \
        o0.y += p[0]*buf0[0].y + p[1]*buf0[1].y + p[2]*buf0[2].y + p[3]*buf0[3].y; \
        o0.z += p[0]*buf0[0].z + p[1]*buf0[1].z + p[2]*buf0[2].z + p[3]*buf0[3].z; \
        o0.w += p[0]*buf0[0].w + p[1]*buf0[1].w + p[2]*buf0[2].w + p[3]*buf0[3].w; \
        o1.x += p[0]*buf1[0].x + p[1]*buf1[1].x + p[2]*buf1[2].x + p[3]*buf1[3].x; \
        o1.y += p[0]*buf1[0].y + p[1]*buf1[1].y + p[2]*buf1[2].y + p[3]*buf1[3].y; \
        o1.z += p[0]*buf1[0].z + p[1]*buf1[1].z + p[2]*buf1[2].z + p[3]*buf1[3].z; \
        o1.w += p[0]*buf1[0].w + p[1]*buf1[1].w + p[2]*buf1[2].w + p[3]*buf1[3].w; \
    }                                                                          \
} while (0)

    // Software pipeline: loads for iteration k+1 are issued before the
    // reduce/softmax of iteration k. 16 iterations total (k = 0..15).
    LOADROWS(A0, A1, 0);
    for (int j = 0; j < 8; ++j) {
        LOADROWS(B0, B1, 2 * j + 1);
        PROCESS(A0, A1, 2 * j);
        if (j < 7) LOADROWS(A0, A1, 2 * j + 2);
        PROCESS(B0, B1, 2 * j + 1);
    }

#undef LOADROWS
#undef PROCESS

    // ---- combine the 4 waves of this block ----
    __shared__ float sm[4];
    __shared__ float sl[4];
    __shared__ float so[4][D];   // 8 KiB

    if (lane == 0) { sm[wave] = m; sl[wave] = l; }
    *(float4*)&so[wave][lane * 4]       = o0;
    *(float4*)&so[wave][256 + lane * 4] = o1;
    __syncthreads();

    const float m_blk = fmaxf(fmaxf(sm[0], sm[1]), fmaxf(sm[2], sm[3]));
    const float s0 = __expf(sm[0] - m_blk);
    const float s1 = __expf(sm[1] - m_blk);
    const float s2 = __expf(sm[2] - m_blk);
    const float s3 = __expf(sm[3] - m_blk);
    const float l_blk = sl[0] * s0 + sl[1] * s1 + sl[2] * s2 + sl[3] * s3;

    float* part = partials + (size_t)blk * PART_STRIDE;
    if (tid == 0) { part[0] = m_blk; part[1] = l_blk; }
    for (int d = tid; d < D; d += 256) {
        part[2 + d] = so[0][d] * s0 + so[1][d] * s1
                    + so[2][d] * s2 + so[3][d] * s3;
    }
}

// ---------------------------------------------------------------------------
// Pass 2: grid = B*4 blocks. Each block redundantly reduces its batch's 16
// chunk partials -> (m_g, l_g); slice 0 also writes ctx. Each block then
// transforms a 1024-element quarter of the weights row, float4-vectorized
// (256 thr x 4 elems, exact).
// ---------------------------------------------------------------------------
__global__ __launch_bounds__(256) void attn_pass2(
    const float* __restrict__ partials,   // [B*CHUNKS, PART_STRIDE]
    float* __restrict__ ctx,              // [B, D] (d_out head)
    float* __restrict__ weights)          // [B, T] (in-place energies)
{
    const int b     = blockIdx.x >> 2;
    const int slice = blockIdx.x & 3;
    const int tid   = threadIdx.x;
    const float* pb = partials + (size_t)b * CHUNKS * PART_STRIDE;

    float m_g = -3.0e38f;
    #pragma unroll
    for (int c = 0; c < CHUNKS; ++c)
        m_g = fmaxf(m_g, pb[c * PART_STRIDE]);

    float sc[CHUNKS];
    float l_g = 0.0f;
    #pragma unroll
    for (int c = 0; c < CHUNKS; ++c) {
        const float s = __expf(pb[c * PART_STRIDE] - m_g);
        sc[c] = s;
        l_g += pb[c * PART_STRIDE + 1] * s;
    }
    const float inv_l = 1.0f / l_g;

    if (slice == 0) {
        for (int d = tid; d < D; d += 256) {
            float acc = 0.0f;
            #pragma unroll
            for (int c = 0; c < CHUNKS; ++c)
                acc += pb[c * PART_STRIDE + 2 + d] * sc[c];
            ctx[(size_t)b * D + d] = acc * inv_l;
        }
    }

    // quarter-row weight transform, float4-vectorized
    float* wrow = weights + (size_t)b * T + slice * (T / 4);
    float4 w = *(float4*)(wrow + tid * 4);
    w.x = __expf(w.x - m_g) * inv_l;
    w.y = __expf(w.y - m_g) * inv_l;
    w.z = __expf(w.z - m_g) * inv_l;
    w.w = __expf(w.w - m_g) * inv_l;
    *(float4*)(wrow + tid * 4) = w;
}

extern "C" void kernel_launch(void* const* d_in, const int* in_sizes, int n_in,
                              void* d_out, int out_size, void* d_ws, size_t ws_size,
                              hipStream_t stream) {
    const float* enc = (const float*)d_in[0];   // [B,T,D] fp32
    const float* v   = (const float*)d_in[1];   // [D,1]   fp32
    float* out     = (float*)d_out;
    float* ctx     = out;            // first B*D floats
    float* weights = out + B * D;    // next  B*T floats (also energy scratch)
    float* partials = (float*)d_ws;  // B*CHUNKS*PART_STRIDE*4 ≈ 2.1 MB

    attn_pass1<<<B * CHUNKS, 256, 0, stream>>>(enc, v, weights, partials);
    attn_pass2<<<B * 4, 256, 0, stream>>>(partials, ctx, weights);
}